// Round 7
// baseline (1209.558 us; speedup 1.0000x reference)
//
#include <hip/hip_runtime.h>
#include <math.h>

#define NSD 9
#define NPD 2
#define NAD 7
#define NH  256
#define NIN 16   // NSD + NAD

typedef _Float16 half8 __attribute__((ext_vector_type(8)));
typedef _Float16 half4 __attribute__((ext_vector_type(4)));
typedef float    floatx4 __attribute__((ext_vector_type(4)));

#define H2S 260            // h2R fp32 row stride (260 % 32 = 4 -> spread, R1-verified)
#define FRAG_SZ 552        // halves per A-frag slot (verified layout since R5)
#define LOSCALE 2048.0f
#define LOINV   (1.0f / 2048.0f)

// ---------------------------------------------------------------------------
// Pack w2 (fp32 [256][256]) into MFMA B-fragment-major fp16 hi/lo arrays.
// (verified since R3 — unchanged)
// ---------------------------------------------------------------------------
__global__ __launch_bounds__(64) void k_pack(const float* __restrict__ w2,
                                             _Float16* __restrict__ w2p)
{
    const int bid  = blockIdx.x;          // t*8 + kc
    const int lane = threadIdx.x;
    const int t = bid >> 3, kc = bid & 7;
    const int ln = lane & 15, quad = lane >> 4;
    half8 hv, lv;
#pragma unroll
    for (int j = 0; j < 8; ++j) {
        const int k = kc * 32 + quad * 8 + j;
        const int n = t * 16 + ln;
        const float x = w2[k * NH + n];
        const _Float16 h = (_Float16)x;
        hv[j] = h;
        lv[j] = (_Float16)((x - (float)h) * LOSCALE);
    }
    *(half8*)&w2p[(size_t)(bid * 2 + 0) * 512 + lane * 8] = hv;
    *(half8*)&w2p[(size_t)(bid * 2 + 1) * 512 + lane * 8] = lv;
}

// ---------------------------------------------------------------------------
// Kernel 1: action proposal + candidate generation (unchanged, verified).
// ---------------------------------------------------------------------------
__global__ __launch_bounds__(256) void k_proposal(
    const float* __restrict__ state, const float* __restrict__ proprio,
    const float* __restrict__ noise, const float* __restrict__ pw1,
    const float* __restrict__ pb1, const float* __restrict__ pw2,
    const float* __restrict__ pb2, float* __restrict__ cand, int B)
{
    const int wave = threadIdx.x >> 6;
    const int lane = threadIdx.x & 63;
    const int b = blockIdx.x * 4 + wave;
    if (b >= B) return;

    float x[11];
#pragma unroll
    for (int k = 0; k < 9; ++k) x[k] = state[b * NSD + k];
    x[9]  = proprio[b * NPD + 0];
    x[10] = proprio[b * NPD + 1];

    float hc[4];
#pragma unroll
    for (int i = 0; i < 4; ++i) {
        const int c = lane + 64 * i;
        float acc = pb1[c];
#pragma unroll
        for (int k = 0; k < 11; ++k) acc = fmaf(x[k], pw1[k * NH + c], acc);
        hc[i] = fmaxf(acc, 0.0f);
    }

    float base[7];
#pragma unroll
    for (int j = 0; j < 7; ++j) {
        float p = 0.0f;
#pragma unroll
        for (int i = 0; i < 4; ++i)
            p = fmaf(hc[i], pw2[(lane + 64 * i) * NAD + j], p);
#pragma unroll
        for (int off = 32; off >= 1; off >>= 1) p += __shfl_xor(p, off, 64);
        base[j] = tanhf(p + pb2[j]);
    }

    if (lane < 8 * NAD) {
        const int s = lane / NAD, j = lane % NAD;
        float bj = base[0];
#pragma unroll
        for (int jj = 1; jj < 7; ++jj) if (j == jj) bj = base[jj];
        float v = bj + 0.2f * noise[((size_t)s * B + b) * NAD + j];
        v = fminf(fmaxf(v, -1.0f), 1.0f);
        cand[((size_t)s * B + b) * NAD + j] = v;
    }
}

// ---------------------------------------------------------------------------
// Kernel 2: rollout. R7 = R6 structure with the occupancy actually enforced:
//  - __launch_bounds__(256, 4): 128-VGPR cap -> 4 waves/SIMD; with 39.4 KB
//    LDS x 4 = 157.7 KB <= 160 KB -> 4 blocks/CU co-resident.
//  - P2 runs TWO kc passes (hi-B then lo-B) so the live set fits 128 VGPRs:
//    pass1: acc1 += ha*hb, acc2 += la*hb (only hb loaded)
//    pass2: acc2 += ha*lb               (only lb loaded, ha re-read from LDS)
// h2R still aliases the h1 frag buffers (barrier before overwrite).
// ---------------------------------------------------------------------------
__global__ __launch_bounds__(256, 4) void k_rollout(
    const float* __restrict__ state, const float* __restrict__ target,
    const float* __restrict__ cand,
    const float* __restrict__ w1, const float* __restrict__ b1,
    const _Float16* __restrict__ w2p, const float* __restrict__ b2,
    const float* __restrict__ w3, const float* __restrict__ b3,
    const int* __restrict__ hor_ptr, float* __restrict__ cost, int B)
{
    __shared__ float    inpR[32][20];
    __shared__ _Float16 fragbuf[2][16 * FRAG_SZ]; // [0]=h1hi,[1]=h1lo; 35.3 KB
                                                  // aliased by h2R fp32[32][260]
    __shared__ float    tgt[32][4];
    __shared__ float    sq[32][4];
    __shared__ float    costAcc[32];

    _Float16* h1hi = fragbuf[0];
    _Float16* h1lo = fragbuf[1];
    float*    h2R  = (float*)fragbuf;

    const int tid = threadIdx.x;
    const int p0 = blockIdx.x * 32;   // B % 32 == 0 -> block never straddles s
    const int s  = p0 / B;
    const int b0 = p0 % B;

    for (int idx = tid; idx < 32 * NSD; idx += 256) {
        const int r = idx / NSD, k = idx % NSD;
        inpR[r][k] = state[(b0 + r) * NSD + k];
    }
    if (tid < 32 * NAD) {
        const int r = tid / NAD, j = tid % NAD;
        inpR[r][NSD + j] = cand[((size_t)s * B + (b0 + r)) * NAD + j];
    }
    if (tid < 32 * 3) {
        const int r = tid / 3, c = tid % 3;
        tgt[r][c] = target[(b0 + r) * 3 + c];
    }
    if (tid < 32) costAcc[tid] = 0.0f;
    __syncthreads();

    const int lane = tid & 63;
    const int wv   = tid >> 6;        // 0..3
    const int r0 = wv * 8;            // P1: wave's 8 rows (32 rows total)
    const int c0 = lane * 4;          // P1: lane's 4 cols
    const int ln   = lane & 15;       // P2 frag coords
    const int quad = lane >> 4;
    const int horizon = *hor_ptr;

    const float4 b1v = *(const float4*)&b1[c0];
    // P1 epilogue frag-packed destination pieces (value (r, c0..c0+3)):
    const int kcq   = lane >> 3;            // k-chunk of c0
    const int quadp = (lane >> 1) & 3;      // quad-of-32 of c0
    const int j0    = (lane & 1) * 4;       // j offset within quad-block
    // P2: wave covers n-tiles t = wv*4 + nt, nt = 0..3
    float bbv[4];
#pragma unroll
    for (int nt = 0; nt < 4; ++nt) bbv[nt] = b2[(wv * 4 + nt) * 16 + ln];

    for (int h = 0; h < horizon; ++h) {
        // ---- P1: h1 = relu(inp @ w1 + b1), fp32, split to frag LDS ----
        {
            float acc[8][4];
#pragma unroll
            for (int i = 0; i < 8; ++i) {
                acc[i][0] = b1v.x; acc[i][1] = b1v.y;
                acc[i][2] = b1v.z; acc[i][3] = b1v.w;
            }
#pragma unroll
            for (int k = 0; k < NIN; k += 4) {
                float4 a[8];
#pragma unroll
                for (int i = 0; i < 8; ++i) a[i] = *(const float4*)&inpR[r0 + i][k];
                const float4 wv0 = *(const float4*)&w1[(k + 0) * NH + c0];
                const float4 wv1 = *(const float4*)&w1[(k + 1) * NH + c0];
                const float4 wv2 = *(const float4*)&w1[(k + 2) * NH + c0];
                const float4 wv3 = *(const float4*)&w1[(k + 3) * NH + c0];
#pragma unroll
                for (int i = 0; i < 8; ++i) {
                    acc[i][0] = fmaf(a[i].x, wv0.x, acc[i][0]);
                    acc[i][1] = fmaf(a[i].x, wv0.y, acc[i][1]);
                    acc[i][2] = fmaf(a[i].x, wv0.z, acc[i][2]);
                    acc[i][3] = fmaf(a[i].x, wv0.w, acc[i][3]);
                    acc[i][0] = fmaf(a[i].y, wv1.x, acc[i][0]);
                    acc[i][1] = fmaf(a[i].y, wv1.y, acc[i][1]);
                    acc[i][2] = fmaf(a[i].y, wv1.z, acc[i][2]);
                    acc[i][3] = fmaf(a[i].y, wv1.w, acc[i][3]);
                    acc[i][0] = fmaf(a[i].z, wv2.x, acc[i][0]);
                    acc[i][1] = fmaf(a[i].z, wv2.y, acc[i][1]);
                    acc[i][2] = fmaf(a[i].z, wv2.z, acc[i][2]);
                    acc[i][3] = fmaf(a[i].z, wv2.w, acc[i][3]);
                    acc[i][0] = fmaf(a[i].w, wv3.x, acc[i][0]);
                    acc[i][1] = fmaf(a[i].w, wv3.y, acc[i][1]);
                    acc[i][2] = fmaf(a[i].w, wv3.z, acc[i][2]);
                    acc[i][3] = fmaf(a[i].w, wv3.w, acc[i][3]);
                }
            }
#pragma unroll
            for (int i = 0; i < 8; ++i) {
                const int r = r0 + i;                       // 0..31
                const int fidx = ((r >> 4) * 8 + kcq) * FRAG_SZ
                               + quadp * 136 + (r & 15) * 8 + j0;
                half4 hv, lv;
#pragma unroll
                for (int q = 0; q < 4; ++q) {
                    const float v = fmaxf(acc[i][q], 0.0f);
                    const _Float16 hh = (_Float16)v;
                    hv[q] = hh;
                    lv[q] = (_Float16)((v - (float)hh) * LOSCALE);
                }
                *(half4*)&h1hi[fidx] = hv;
                *(half4*)&h1lo[fidx] = lv;
            }
        }
        __syncthreads();

        // ---- P2: h2 = relu(h1 @ w2 + b2), split-fp16 MFMA, two kc passes ----
        {
            const int aoff = quad * 136 + ln * 8;
            floatx4 a1[2][4], a2[2][4];
#pragma unroll
            for (int mt = 0; mt < 2; ++mt)
#pragma unroll
                for (int nt = 0; nt < 4; ++nt) {
                    a1[mt][nt] = (floatx4){0.f, 0.f, 0.f, 0.f};
                    a2[mt][nt] = (floatx4){0.f, 0.f, 0.f, 0.f};
                }
            // pass 1: hi-B  (acc1 += ha*hb, acc2 += la*hb)
#pragma unroll
            for (int kc = 0; kc < 8; ++kc) {
                half8 hb[4];
#pragma unroll
                for (int nt = 0; nt < 4; ++nt) {
                    const size_t fo =
                        (size_t)((((wv * 4 + nt) * 8 + kc) * 2)) * 512 + lane * 8;
                    hb[nt] = *(const half8*)&w2p[fo];
                }
#pragma unroll
                for (int mt = 0; mt < 2; ++mt) {
                    const int ao = (mt * 8 + kc) * FRAG_SZ + aoff;
                    const half8 ha = *(const half8*)&h1hi[ao];
                    const half8 la = *(const half8*)&h1lo[ao];
#pragma unroll
                    for (int nt = 0; nt < 4; ++nt) {
                        a1[mt][nt] = __builtin_amdgcn_mfma_f32_16x16x32_f16(
                            ha, hb[nt], a1[mt][nt], 0, 0, 0);
                        a2[mt][nt] = __builtin_amdgcn_mfma_f32_16x16x32_f16(
                            la, hb[nt], a2[mt][nt], 0, 0, 0);
                    }
                }
            }
            // pass 2: lo-B  (acc2 += ha*lb)
#pragma unroll
            for (int kc = 0; kc < 8; ++kc) {
                half8 lb[4];
#pragma unroll
                for (int nt = 0; nt < 4; ++nt) {
                    const size_t fo =
                        (size_t)((((wv * 4 + nt) * 8 + kc) * 2)) * 512 + lane * 8;
                    lb[nt] = *(const half8*)&w2p[fo + 512];
                }
#pragma unroll
                for (int mt = 0; mt < 2; ++mt) {
                    const int ao = (mt * 8 + kc) * FRAG_SZ + aoff;
                    const half8 ha = *(const half8*)&h1hi[ao];
#pragma unroll
                    for (int nt = 0; nt < 4; ++nt) {
                        a2[mt][nt] = __builtin_amdgcn_mfma_f32_16x16x32_f16(
                            ha, lb[nt], a2[mt][nt], 0, 0, 0);
                    }
                }
            }
            __syncthreads();   // all frag reads done -> safe to overwrite (alias)
#pragma unroll
            for (int mt = 0; mt < 2; ++mt)
#pragma unroll
                for (int nt = 0; nt < 4; ++nt) {
                    const int n = (wv * 4 + nt) * 16 + ln;
#pragma unroll
                    for (int r = 0; r < 4; ++r) {
                        const float v =
                            fmaf(a2[mt][nt][r], LOINV, a1[mt][nt][r]) + bbv[nt];
                        h2R[(mt * 16 + quad * 4 + r) * H2S + n] = fmaxf(v, 0.0f);
                    }
                }
        }
        __syncthreads();

        // ---- P3: sim' = h2 @ w3 + b3; cost term (fp32 VALU) ----
        for (int idx = tid; idx < 32 * NSD; idx += 256) {
            const int r = idx / NSD, j = idx - (idx / NSD) * NSD;
            float a0 = 0.f, a1 = 0.f, a2 = 0.f, a3 = 0.f;
#pragma unroll 4
            for (int k = 0; k < NH; k += 4) {
                const float4 hv2 = *(const float4*)&h2R[r * H2S + k];
                a0 = fmaf(hv2.x, w3[(k + 0) * NSD + j], a0);
                a1 = fmaf(hv2.y, w3[(k + 1) * NSD + j], a1);
                a2 = fmaf(hv2.z, w3[(k + 2) * NSD + j], a2);
                a3 = fmaf(hv2.w, w3[(k + 3) * NSD + j], a3);
            }
            const float accv = b3[j] + ((a0 + a1) + (a2 + a3));
            inpR[r][j] = accv;
            if (j < 3) { const float d = accv - tgt[r][j]; sq[r][j] = d * d; }
        }
        __syncthreads();
        if (tid < 32) costAcc[tid] += sq[tid][0] + sq[tid][1] + sq[tid][2];
    }

    if (tid < 32) cost[(size_t)s * B + b0 + tid] = costAcc[tid];
}

// ---------------------------------------------------------------------------
// Kernel 3: first-argmin over samples + gather best action (unchanged).
// ---------------------------------------------------------------------------
__global__ __launch_bounds__(256) void k_select(
    const float* __restrict__ cost, const float* __restrict__ cand,
    float* __restrict__ out, int B, int S)
{
    const int b = blockIdx.x * 256 + threadIdx.x;
    if (b >= B) return;
    float best = cost[b];
    int bs = 0;
    for (int s = 1; s < S; ++s) {
        const float c = cost[(size_t)s * B + b];
        if (c < best) { best = c; bs = s; }
    }
#pragma unroll
    for (int j = 0; j < NAD; ++j)
        out[b * NAD + j] = cand[((size_t)bs * B + b) * NAD + j];
}

// ---------------------------------------------------------------------------
extern "C" void kernel_launch(void* const* d_in, const int* in_sizes, int n_in,
                              void* d_out, int out_size, void* d_ws, size_t ws_size,
                              hipStream_t stream)
{
    const float* state   = (const float*)d_in[0];
    const float* proprio = (const float*)d_in[1];
    const float* target  = (const float*)d_in[2];
    const float* noise   = (const float*)d_in[3];
    const float* pw1     = (const float*)d_in[4];
    const float* pb1     = (const float*)d_in[5];
    const float* pw2     = (const float*)d_in[6];
    const float* pb2     = (const float*)d_in[7];
    const float* w1      = (const float*)d_in[8];
    const float* b1      = (const float*)d_in[9];
    const float* w2      = (const float*)d_in[10];
    const float* b2      = (const float*)d_in[11];
    const float* w3      = (const float*)d_in[12];
    const float* b3      = (const float*)d_in[13];
    const int*   horizon = (const int*)d_in[14];

    const int B = in_sizes[0] / NSD;             // 8192
    const int S = in_sizes[3] / (B * NAD);       // 8

    float* cand = (float*)d_ws;                           // S*B*7 floats
    float* cost = cand + (size_t)S * B * NAD;             // S*B floats
    _Float16* w2p = (_Float16*)(cost + (size_t)S * B);    // 128 KB hi + 128 KB lo
    float* out  = (float*)d_out;

    k_pack<<<dim3(128), dim3(64), 0, stream>>>(w2, w2p);
    k_proposal<<<dim3((B + 3) / 4), dim3(256), 0, stream>>>(
        state, proprio, noise, pw1, pb1, pw2, pb2, cand, B);
    k_rollout<<<dim3((S * B) / 32), dim3(256), 0, stream>>>(
        state, target, cand, w1, b1, w2p, b2, w3, b3, horizon, cost, B);
    k_select<<<dim3((B + 255) / 256), dim3(256), 0, stream>>>(
        cost, cand, out, B, S);
}

// Round 8
// 459.691 us; speedup vs baseline: 2.6312x; 2.6312x over previous
//
#include <hip/hip_runtime.h>
#include <math.h>

#define NSD 9
#define NPD 2
#define NAD 7
#define NH  256
#define NIN 16   // NSD + NAD

typedef _Float16 half8 __attribute__((ext_vector_type(8)));
typedef _Float16 half4 __attribute__((ext_vector_type(4)));
typedef float    floatx4 __attribute__((ext_vector_type(4)));

#define H2S 260            // h2R fp32 row stride (260 % 32 = 4 -> spread, R1-verified)
#define FRAG_H 528         // fp16 units per A-frag slot (R3-verified layout)
#define LOSCALE 2048.0f
#define LOINV   (1.0f / 2048.0f)

// ---------------------------------------------------------------------------
// Pack w2 (fp32 [256][256]) into MFMA B-fragment-major fp16 hi/lo arrays.
// (verified since R3 — unchanged)
// ---------------------------------------------------------------------------
__global__ __launch_bounds__(64) void k_pack(const float* __restrict__ w2,
                                             _Float16* __restrict__ w2p)
{
    const int bid  = blockIdx.x;          // t*8 + kc
    const int lane = threadIdx.x;
    const int t = bid >> 3, kc = bid & 7;
    const int ln = lane & 15, quad = lane >> 4;
    half8 hv, lv;
#pragma unroll
    for (int j = 0; j < 8; ++j) {
        const int k = kc * 32 + quad * 8 + j;
        const int n = t * 16 + ln;
        const float x = w2[k * NH + n];
        const _Float16 h = (_Float16)x;
        hv[j] = h;
        lv[j] = (_Float16)((x - (float)h) * LOSCALE);
    }
    *(half8*)&w2p[(size_t)(bid * 2 + 0) * 512 + lane * 8] = hv;
    *(half8*)&w2p[(size_t)(bid * 2 + 1) * 512 + lane * 8] = lv;
}

// ---------------------------------------------------------------------------
// Kernel 1: action proposal + candidate generation (unchanged, verified).
// ---------------------------------------------------------------------------
__global__ __launch_bounds__(256) void k_proposal(
    const float* __restrict__ state, const float* __restrict__ proprio,
    const float* __restrict__ noise, const float* __restrict__ pw1,
    const float* __restrict__ pb1, const float* __restrict__ pw2,
    const float* __restrict__ pb2, float* __restrict__ cand, int B)
{
    const int wave = threadIdx.x >> 6;
    const int lane = threadIdx.x & 63;
    const int b = blockIdx.x * 4 + wave;
    if (b >= B) return;

    float x[11];
#pragma unroll
    for (int k = 0; k < 9; ++k) x[k] = state[b * NSD + k];
    x[9]  = proprio[b * NPD + 0];
    x[10] = proprio[b * NPD + 1];

    float hc[4];
#pragma unroll
    for (int i = 0; i < 4; ++i) {
        const int c = lane + 64 * i;
        float acc = pb1[c];
#pragma unroll
        for (int k = 0; k < 11; ++k) acc = fmaf(x[k], pw1[k * NH + c], acc);
        hc[i] = fmaxf(acc, 0.0f);
    }

    float base[7];
#pragma unroll
    for (int j = 0; j < 7; ++j) {
        float p = 0.0f;
#pragma unroll
        for (int i = 0; i < 4; ++i)
            p = fmaf(hc[i], pw2[(lane + 64 * i) * NAD + j], p);
#pragma unroll
        for (int off = 32; off >= 1; off >>= 1) p += __shfl_xor(p, off, 64);
        base[j] = tanhf(p + pb2[j]);
    }

    if (lane < 8 * NAD) {
        const int s = lane / NAD, j = lane % NAD;
        float bj = base[0];
#pragma unroll
        for (int jj = 1; jj < 7; ++jj) if (j == jj) bj = base[jj];
        float v = bj + 0.2f * noise[((size_t)s * B + b) * NAD + j];
        v = fminf(fmaxf(v, -1.0f), 1.0f);
        cand[((size_t)s * B + b) * NAD + j] = v;
    }
}

// ---------------------------------------------------------------------------
// Kernel 2: rollout. R8 = the R3 kernel (verified 385 us, 104 VGPR, no
// spill) with ONE change: h2R (fp32 [64][260]) aliases the h1 hi/lo frag
// buffers (h1 dead after P2's frag reads; extra barrier before overwrite).
// LDS 138.5 -> 73.3 KB => 2 blocks/CU (4 waves/SIMD) for latency hiding.
// NO launch-bounds VGPR coercion (R4/R5/R7 all spilled or were ignored).
// ---------------------------------------------------------------------------
__global__ __launch_bounds__(512) void k_rollout(
    const float* __restrict__ state, const float* __restrict__ target,
    const float* __restrict__ cand,
    const float* __restrict__ w1, const float* __restrict__ b1,
    const _Float16* __restrict__ w2p, const float* __restrict__ b2,
    const float* __restrict__ w3, const float* __restrict__ b3,
    const int* __restrict__ hor_ptr, float* __restrict__ cost, int B)
{
    __shared__ float    inpR[64][20];
    __shared__ _Float16 fragbuf[2][32 * FRAG_H];  // 66 KB; [0]=h1hi,[1]=h1lo
                                                  // aliased by h2R fp32[64][260] (65 KB)
    __shared__ float    tgt[64][4];
    __shared__ float    sq[64][4];
    __shared__ float    costAcc[64];

    _Float16* h1hi = fragbuf[0];
    _Float16* h1lo = fragbuf[1];
    float*    h2R  = (float*)fragbuf;

    const int tid = threadIdx.x;
    const int p0 = blockIdx.x * 64;
    const int s  = p0 / B;
    const int b0 = p0 % B;

    for (int idx = tid; idx < 64 * NSD; idx += 512) {
        const int r = idx / NSD, k = idx % NSD;
        inpR[r][k] = state[(b0 + r) * NSD + k];
    }
    if (tid < 64 * NAD) {
        const int r = tid / NAD, j = tid % NAD;
        inpR[r][NSD + j] = cand[((size_t)s * B + (b0 + r)) * NAD + j];
    }
    if (tid < 64 * 3) {
        const int r = tid / 3, c = tid % 3;
        tgt[r][c] = target[(b0 + r) * 3 + c];
    }
    if (tid < 64) costAcc[tid] = 0.0f;
    __syncthreads();

    const int lane = tid & 63;
    const int wv   = tid >> 6;
    const int r0 = wv * 8;            // P1: wave's 8 rows
    const int c0 = lane * 4;          // P1: lane's 4 cols
    const int ln   = lane & 15;       // P2 frag coords
    const int quad = lane >> 4;
    const int horizon = *hor_ptr;

    const float4 b1v = *(const float4*)&b1[c0];
    // P1 epilogue frag-packed destination pieces (value (r, c0..c0+3)):
    const int kcq   = lane >> 3;            // k-chunk of c0
    const int quadp = (lane >> 1) & 3;      // quad-of-32 of c0
    const int j0    = (lane & 1) * 4;       // j offset within quad-block
    const float bb0 = b2[wv * 32 + ln];
    const float bb1 = b2[wv * 32 + 16 + ln];

    for (int h = 0; h < horizon; ++h) {
        // ---- P1: h1 = relu(inp @ w1 + b1), fp32, split to frag LDS ----
        {
            float acc[8][4];
#pragma unroll
            for (int i = 0; i < 8; ++i) {
                acc[i][0] = b1v.x; acc[i][1] = b1v.y;
                acc[i][2] = b1v.z; acc[i][3] = b1v.w;
            }
#pragma unroll
            for (int k = 0; k < NIN; k += 4) {
                float4 a[8];
#pragma unroll
                for (int i = 0; i < 8; ++i) a[i] = *(const float4*)&inpR[r0 + i][k];
                const float4 wv0 = *(const float4*)&w1[(k + 0) * NH + c0];
                const float4 wv1 = *(const float4*)&w1[(k + 1) * NH + c0];
                const float4 wv2 = *(const float4*)&w1[(k + 2) * NH + c0];
                const float4 wv3 = *(const float4*)&w1[(k + 3) * NH + c0];
#pragma unroll
                for (int i = 0; i < 8; ++i) {
                    acc[i][0] = fmaf(a[i].x, wv0.x, acc[i][0]);
                    acc[i][1] = fmaf(a[i].x, wv0.y, acc[i][1]);
                    acc[i][2] = fmaf(a[i].x, wv0.z, acc[i][2]);
                    acc[i][3] = fmaf(a[i].x, wv0.w, acc[i][3]);
                    acc[i][0] = fmaf(a[i].y, wv1.x, acc[i][0]);
                    acc[i][1] = fmaf(a[i].y, wv1.y, acc[i][1]);
                    acc[i][2] = fmaf(a[i].y, wv1.z, acc[i][2]);
                    acc[i][3] = fmaf(a[i].y, wv1.w, acc[i][3]);
                    acc[i][0] = fmaf(a[i].z, wv2.x, acc[i][0]);
                    acc[i][1] = fmaf(a[i].z, wv2.y, acc[i][1]);
                    acc[i][2] = fmaf(a[i].z, wv2.z, acc[i][2]);
                    acc[i][3] = fmaf(a[i].z, wv2.w, acc[i][3]);
                    acc[i][0] = fmaf(a[i].w, wv3.x, acc[i][0]);
                    acc[i][1] = fmaf(a[i].w, wv3.y, acc[i][1]);
                    acc[i][2] = fmaf(a[i].w, wv3.z, acc[i][2]);
                    acc[i][3] = fmaf(a[i].w, wv3.w, acc[i][3]);
                }
            }
#pragma unroll
            for (int i = 0; i < 8; ++i) {
                const int r = r0 + i;
                const int fidx = ((r >> 4) * 8 + kcq) * FRAG_H
                               + (quadp * 16 + (r & 15)) * 8 + j0;
                half4 hv, lv;
#pragma unroll
                for (int q = 0; q < 4; ++q) {
                    const float v = fmaxf(acc[i][q], 0.0f);
                    const _Float16 hh = (_Float16)v;
                    hv[q] = hh;
                    lv[q] = (_Float16)((v - (float)hh) * LOSCALE);
                }
                *(half4*)&h1hi[fidx] = hv;
                *(half4*)&h1lo[fidx] = lv;
            }
        }
        __syncthreads();

        // ---- P2: h2 = relu(h1 @ w2 + b2) via split-fp16 MFMA ----
        {
            floatx4 acc1[4][2], acc2[4][2];
#pragma unroll
            for (int mt = 0; mt < 4; ++mt)
#pragma unroll
                for (int nt = 0; nt < 2; ++nt) {
                    acc1[mt][nt] = (floatx4){0.f, 0.f, 0.f, 0.f};
                    acc2[mt][nt] = (floatx4){0.f, 0.f, 0.f, 0.f};
                }
#pragma unroll 2
            for (int kc = 0; kc < 8; ++kc) {
                half8 hb[2], lb[2];
#pragma unroll
                for (int nt = 0; nt < 2; ++nt) {
                    const size_t fo =
                        (size_t)((((wv * 2 + nt) * 8 + kc) * 2)) * 512 + lane * 8;
                    hb[nt] = *(const half8*)&w2p[fo];
                    lb[nt] = *(const half8*)&w2p[fo + 512];
                }
                half8 ha[4], la[4];
#pragma unroll
                for (int mt = 0; mt < 4; ++mt) {
                    const int ao = (mt * 8 + kc) * FRAG_H + lane * 8;
                    ha[mt] = *(const half8*)&h1hi[ao];
                    la[mt] = *(const half8*)&h1lo[ao];
                }
#pragma unroll
                for (int mt = 0; mt < 4; ++mt)
#pragma unroll
                    for (int nt = 0; nt < 2; ++nt) {
                        acc1[mt][nt] = __builtin_amdgcn_mfma_f32_16x16x32_f16(
                            ha[mt], hb[nt], acc1[mt][nt], 0, 0, 0);
                        acc2[mt][nt] = __builtin_amdgcn_mfma_f32_16x16x32_f16(
                            ha[mt], lb[nt], acc2[mt][nt], 0, 0, 0);
                        acc2[mt][nt] = __builtin_amdgcn_mfma_f32_16x16x32_f16(
                            la[mt], hb[nt], acc2[mt][nt], 0, 0, 0);
                    }
            }
            __syncthreads();   // all frag reads done -> safe to overwrite (h2R aliases h1)
#pragma unroll
            for (int mt = 0; mt < 4; ++mt)
#pragma unroll
                for (int nt = 0; nt < 2; ++nt) {
                    const float bb = nt ? bb1 : bb0;
                    const int n = wv * 32 + nt * 16 + ln;
#pragma unroll
                    for (int r = 0; r < 4; ++r) {
                        const float v = fmaf(acc2[mt][nt][r], LOINV, acc1[mt][nt][r]) + bb;
                        h2R[(mt * 16 + quad * 4 + r) * H2S + n] = fmaxf(v, 0.0f);
                    }
                }
        }
        __syncthreads();

        // ---- P3: sim' = h2 @ w3 + b3; cost term (fp32 VALU) ----
        for (int idx = tid; idx < 64 * NSD; idx += 512) {
            const int r = idx / NSD, j = idx - (idx / NSD) * NSD;
            float a0 = 0.f, a1 = 0.f, a2 = 0.f, a3 = 0.f;
#pragma unroll 4
            for (int k = 0; k < NH; k += 4) {
                const float4 hv2 = *(const float4*)&h2R[r * H2S + k];
                a0 = fmaf(hv2.x, w3[(k + 0) * NSD + j], a0);
                a1 = fmaf(hv2.y, w3[(k + 1) * NSD + j], a1);
                a2 = fmaf(hv2.z, w3[(k + 2) * NSD + j], a2);
                a3 = fmaf(hv2.w, w3[(k + 3) * NSD + j], a3);
            }
            const float accv = b3[j] + ((a0 + a1) + (a2 + a3));
            inpR[r][j] = accv;
            if (j < 3) { const float d = accv - tgt[r][j]; sq[r][j] = d * d; }
        }
        __syncthreads();
        if (tid < 64) costAcc[tid] += sq[tid][0] + sq[tid][1] + sq[tid][2];
    }

    if (tid < 64) cost[(size_t)s * B + b0 + tid] = costAcc[tid];
}

// ---------------------------------------------------------------------------
// Kernel 3: first-argmin over samples + gather best action (unchanged).
// ---------------------------------------------------------------------------
__global__ __launch_bounds__(256) void k_select(
    const float* __restrict__ cost, const float* __restrict__ cand,
    float* __restrict__ out, int B, int S)
{
    const int b = blockIdx.x * 256 + threadIdx.x;
    if (b >= B) return;
    float best = cost[b];
    int bs = 0;
    for (int s = 1; s < S; ++s) {
        const float c = cost[(size_t)s * B + b];
        if (c < best) { best = c; bs = s; }
    }
#pragma unroll
    for (int j = 0; j < NAD; ++j)
        out[b * NAD + j] = cand[((size_t)bs * B + b) * NAD + j];
}

// ---------------------------------------------------------------------------
extern "C" void kernel_launch(void* const* d_in, const int* in_sizes, int n_in,
                              void* d_out, int out_size, void* d_ws, size_t ws_size,
                              hipStream_t stream)
{
    const float* state   = (const float*)d_in[0];
    const float* proprio = (const float*)d_in[1];
    const float* target  = (const float*)d_in[2];
    const float* noise   = (const float*)d_in[3];
    const float* pw1     = (const float*)d_in[4];
    const float* pb1     = (const float*)d_in[5];
    const float* pw2     = (const float*)d_in[6];
    const float* pb2     = (const float*)d_in[7];
    const float* w1      = (const float*)d_in[8];
    const float* b1      = (const float*)d_in[9];
    const float* w2      = (const float*)d_in[10];
    const float* b2      = (const float*)d_in[11];
    const float* w3      = (const float*)d_in[12];
    const float* b3      = (const float*)d_in[13];
    const int*   horizon = (const int*)d_in[14];

    const int B = in_sizes[0] / NSD;             // 8192
    const int S = in_sizes[3] / (B * NAD);       // 8

    float* cand = (float*)d_ws;                           // S*B*7 floats
    float* cost = cand + (size_t)S * B * NAD;             // S*B floats
    _Float16* w2p = (_Float16*)(cost + (size_t)S * B);    // 128 KB hi + 128 KB lo
    float* out  = (float*)d_out;

    k_pack<<<dim3(128), dim3(64), 0, stream>>>(w2, w2p);
    k_proposal<<<dim3((B + 3) / 4), dim3(256), 0, stream>>>(
        state, proprio, noise, pw1, pb1, pw2, pb2, cand, B);
    k_rollout<<<dim3((S * B) / 64), dim3(512), 0, stream>>>(
        state, target, cand, w1, b1, w2p, b2, w3, b3, horizon, cost, B);
    k_select<<<dim3((B + 255) / 256), dim3(256), 0, stream>>>(
        cost, cand, out, B, S);
}